// Round 1
// baseline (964.671 us; speedup 1.0000x reference)
//
#include <hip/hip_runtime.h>
#include <hip/hip_bf16.h>
#include <math.h>

#define EPS 1e-5f

// ---------------------------------------------------------------------------
// Kernel 1: global average pool over H*W=4096 per (b,c).  grid = 32*128 blocks.
// ---------------------------------------------------------------------------
__global__ __launch_bounds__(256) void pool_kernel(const float* __restrict__ x,
                                                   float* __restrict__ pooled) {
    int bc = blockIdx.x;                       // b*128 + c
    const float4* x4 = (const float4*)(x + (size_t)bc * 4096);
    int tid = threadIdx.x;
    float s = 0.f;
#pragma unroll
    for (int i = 0; i < 4; ++i) {
        float4 v = x4[tid + i * 256];
        s += v.x + v.y + v.z + v.w;
    }
#pragma unroll
    for (int off = 32; off > 0; off >>= 1) s += __shfl_down(s, off, 64);
    __shared__ float red[4];
    if ((tid & 63) == 0) red[tid >> 6] = s;
    __syncthreads();
    if (tid == 0) pooled[bc] = (red[0] + red[1] + red[2] + red[3]) * (1.0f / 4096.0f);
}

// ---------------------------------------------------------------------------
// Kernel 2: SE MLP -> att[32,4].  1 block, thread b = sample.
// ---------------------------------------------------------------------------
__global__ void se_kernel(const float* __restrict__ pooled,
                          const float* __restrict__ se_w1,
                          const float* __restrict__ gn1_s, const float* __restrict__ gn1_b,
                          const float* __restrict__ se_w2,
                          const float* __restrict__ gn2_s, const float* __restrict__ gn2_b,
                          float* __restrict__ att) {
    int b = threadIdx.x;
    if (b >= 32) return;
    const float* p = pooled + b * 128;

    float h1[8];
#pragma unroll
    for (int j = 0; j < 8; ++j) {
        float s = 0.f;
        for (int c = 0; c < 128; ++c) s += p[c] * se_w1[j * 128 + c];
        h1[j] = s;
    }
    float m = 0.f;
#pragma unroll
    for (int j = 0; j < 8; ++j) m += h1[j];
    m *= 0.125f;
    float var = 0.f;
#pragma unroll
    for (int j = 0; j < 8; ++j) { float d = h1[j] - m; var += d * d; }
    var *= 0.125f;
    float inv = rsqrtf(var + EPS);
#pragma unroll
    for (int j = 0; j < 8; ++j) {
        float t = (h1[j] - m) * inv * gn1_s[j] + gn1_b[j];
        float sp = (t > 20.f) ? t : log1pf(expf(t));   // softplus
        h1[j] = t * tanhf(sp);                          // mish
    }
    float h2[4];
#pragma unroll
    for (int k = 0; k < 4; ++k) {
        float s = 0.f;
#pragma unroll
        for (int j = 0; j < 8; ++j) s += h1[j] * se_w2[k * 8 + j];
        h2[k] = s;
    }
    float m2 = 0.25f * (h2[0] + h2[1] + h2[2] + h2[3]);
    float v2 = 0.f;
#pragma unroll
    for (int k = 0; k < 4; ++k) { float d = h2[k] - m2; v2 += d * d; }
    v2 *= 0.25f;
    float inv2 = rsqrtf(v2 + EPS);
#pragma unroll
    for (int k = 0; k < 4; ++k) {
        float t = (h2[k] - m2) * inv2 * gn2_s[k] + gn2_b[k];
        att[b * 4 + k] = 1.0f / (1.0f + expf(-t));
    }
}

// ---------------------------------------------------------------------------
// Kernel 3: aggregate weights with att, re-laid as [b][ot(8)][ic(128)][oc16(16)][9]
// so the conv kernel's per-(block,ic) weight chunk (144 floats) is contiguous
// and block-uniform (-> scalar loads).
// total = 32*8*128*16*9 = 4,718,592 elements
// ---------------------------------------------------------------------------
__global__ __launch_bounds__(256) void aggw_kernel(const float* __restrict__ weight,
                                                   const float* __restrict__ att,
                                                   float* __restrict__ aggw) {
    int idx = blockIdx.x * 256 + threadIdx.x;
    if (idx >= 32 * 8 * 128 * 16 * 9) return;
    int j = idx;
    int t9 = j % 9;  j /= 9;
    int oc16 = j % 16; j /= 16;
    int ic = j % 128; j /= 128;
    int ot = j % 8;  int b = j / 8;
    int oc = ot * 16 + oc16;
    const float* a = att + b * 4;
    float s = 0.f;
#pragma unroll
    for (int k = 0; k < 4; ++k)
        s += a[k] * weight[(((size_t)k * 128 + oc) * 128 + ic) * 9 + t9];
    aggw[idx] = s;
}

// ---------------------------------------------------------------------------
// Kernel 4: direct conv.  grid = 32(b) * 8(oc tile) * 16(row tile) blocks,
// 256 threads = 4 rows x 64 cols; each thread: one pixel, 16 oc accumulators.
// Weights are block-uniform -> scalar loads; FMA stream dominates.
// ---------------------------------------------------------------------------
__global__ __launch_bounds__(256) void conv_kernel(const float* __restrict__ x,
                                                   const float* __restrict__ aggw,
                                                   const float* __restrict__ att,
                                                   const float* __restrict__ bias,
                                                   float* __restrict__ out) {
    int blk = blockIdx.x;
    int b  = blk >> 7;          // / 128
    int ot = (blk >> 4) & 7;
    int rt = blk & 15;
    int tid = threadIdx.x;
    int col = tid & 63;
    int row = rt * 4 + (tid >> 6);

    const float* xb = x + (size_t)b * 128 * 4096 + row * 64 + col;
    const float* wb = aggw + (size_t)(b * 8 + ot) * 128 * 144;

    bool rm = row > 0, rp = row < 63, cm = col > 0, cp = col < 63;

    float acc[16];
#pragma unroll
    for (int i = 0; i < 16; ++i) acc[i] = 0.f;

    for (int ic = 0; ic < 128; ++ic) {
        const float* xr = xb + (size_t)ic * 4096;
        float x00 = (rm && cm) ? xr[-65] : 0.f;
        float x01 = rm         ? xr[-64] : 0.f;
        float x02 = (rm && cp) ? xr[-63] : 0.f;
        float x10 = cm         ? xr[-1]  : 0.f;
        float x11 =              xr[0];
        float x12 = cp         ? xr[1]   : 0.f;
        float x20 = (rp && cm) ? xr[63]  : 0.f;
        float x21 = rp         ? xr[64]  : 0.f;
        float x22 = (rp && cp) ? xr[65]  : 0.f;

        const float* w = wb + ic * 144;
#pragma unroll
        for (int oc = 0; oc < 16; ++oc) {
            const float* wo = w + oc * 9;
            float a = acc[oc];
            a = fmaf(wo[0], x00, a);
            a = fmaf(wo[1], x01, a);
            a = fmaf(wo[2], x02, a);
            a = fmaf(wo[3], x10, a);
            a = fmaf(wo[4], x11, a);
            a = fmaf(wo[5], x12, a);
            a = fmaf(wo[6], x20, a);
            a = fmaf(wo[7], x21, a);
            a = fmaf(wo[8], x22, a);
            acc[oc] = a;
        }
    }

    // epilogue: + (att @ bias)[b, oc]
    float a0 = att[b * 4 + 0], a1 = att[b * 4 + 1], a2 = att[b * 4 + 2], a3 = att[b * 4 + 3];
    int ocg0 = ot * 16;
    float* ob = out + (size_t)(b * 128 + ocg0) * 4096 + row * 64 + col;
#pragma unroll
    for (int oc = 0; oc < 16; ++oc) {
        int ocg = ocg0 + oc;
        float ab = a0 * bias[ocg] + a1 * bias[128 + ocg] + a2 * bias[256 + ocg] + a3 * bias[384 + ocg];
        ob[(size_t)oc * 4096] = acc[oc] + ab;
    }
}

// ---------------------------------------------------------------------------
extern "C" void kernel_launch(void* const* d_in, const int* in_sizes, int n_in,
                              void* d_out, int out_size, void* d_ws, size_t ws_size,
                              hipStream_t stream) {
    const float* x      = (const float*)d_in[0];
    const float* weight = (const float*)d_in[1];
    const float* bias   = (const float*)d_in[2];
    const float* se_w1  = (const float*)d_in[3];
    const float* gn1_s  = (const float*)d_in[4];
    const float* gn1_b  = (const float*)d_in[5];
    const float* se_w2  = (const float*)d_in[6];
    const float* gn2_s  = (const float*)d_in[7];
    const float* gn2_b  = (const float*)d_in[8];
    float* out = (float*)d_out;

    // workspace layout
    float* pooled = (float*)d_ws;                          // 4096 floats
    float* att    = (float*)((char*)d_ws + 16384);         // 128 floats
    float* aggw   = (float*)((char*)d_ws + 32768);         // 4,718,592 floats (18 MiB)

    pool_kernel<<<32 * 128, 256, 0, stream>>>(x, pooled);
    se_kernel<<<1, 64, 0, stream>>>(pooled, se_w1, gn1_s, gn1_b, se_w2, gn2_s, gn2_b, att);
    aggw_kernel<<<(32 * 8 * 128 * 16 * 9) / 256, 256, 0, stream>>>(weight, att, aggw);
    conv_kernel<<<32 * 8 * 16, 256, 0, stream>>>(x, aggw, att, bias, out);
}

// Round 2
// 129.421 us; speedup vs baseline: 7.4538x; 7.4538x over previous
//
#include <hip/hip_runtime.h>
#include <hip/hip_bf16.h>
#include <math.h>

#define EPS 1e-5f

typedef __attribute__((ext_vector_type(8))) short bf16x8;
typedef __attribute__((ext_vector_type(4))) float f32x4;

__device__ __forceinline__ ushort f2bf(float f) {
    union { float f; unsigned u; } v; v.f = f;
    unsigned r = (v.u + 0x7FFFu + ((v.u >> 16) & 1u)) >> 16;
    return (ushort)r;
}

// ---------------------------------------------------------------------------
// Kernel 1: global average pool over H*W=4096 per (b,c).  grid = 32*128 blocks.
// ---------------------------------------------------------------------------
__global__ __launch_bounds__(256) void pool_kernel(const float* __restrict__ x,
                                                   float* __restrict__ pooled) {
    int bc = blockIdx.x;
    const float4* x4 = (const float4*)(x + (size_t)bc * 4096);
    int tid = threadIdx.x;
    float s = 0.f;
#pragma unroll
    for (int i = 0; i < 4; ++i) {
        float4 v = x4[tid + i * 256];
        s += v.x + v.y + v.z + v.w;
    }
#pragma unroll
    for (int off = 32; off > 0; off >>= 1) s += __shfl_down(s, off, 64);
    __shared__ float red[4];
    if ((tid & 63) == 0) red[tid >> 6] = s;
    __syncthreads();
    if (tid == 0) pooled[bc] = (red[0] + red[1] + red[2] + red[3]) * (1.0f / 4096.0f);
}

// ---------------------------------------------------------------------------
// Kernel 2: SE MLP -> att[32,4].  1 block, thread b = sample.
// ---------------------------------------------------------------------------
__global__ void se_kernel(const float* __restrict__ pooled,
                          const float* __restrict__ se_w1,
                          const float* __restrict__ gn1_s, const float* __restrict__ gn1_b,
                          const float* __restrict__ se_w2,
                          const float* __restrict__ gn2_s, const float* __restrict__ gn2_b,
                          float* __restrict__ att) {
    int b = threadIdx.x;
    if (b >= 32) return;
    const float* p = pooled + b * 128;

    float h1[8];
#pragma unroll
    for (int j = 0; j < 8; ++j) {
        float s = 0.f;
        for (int c = 0; c < 128; ++c) s += p[c] * se_w1[j * 128 + c];
        h1[j] = s;
    }
    float m = 0.f;
#pragma unroll
    for (int j = 0; j < 8; ++j) m += h1[j];
    m *= 0.125f;
    float var = 0.f;
#pragma unroll
    for (int j = 0; j < 8; ++j) { float d = h1[j] - m; var += d * d; }
    var *= 0.125f;
    float inv = rsqrtf(var + EPS);
#pragma unroll
    for (int j = 0; j < 8; ++j) {
        float t = (h1[j] - m) * inv * gn1_s[j] + gn1_b[j];
        float sp = (t > 20.f) ? t : log1pf(expf(t));
        h1[j] = t * tanhf(sp);
    }
    float h2[4];
#pragma unroll
    for (int k = 0; k < 4; ++k) {
        float s = 0.f;
#pragma unroll
        for (int j = 0; j < 8; ++j) s += h1[j] * se_w2[k * 8 + j];
        h2[k] = s;
    }
    float m2 = 0.25f * (h2[0] + h2[1] + h2[2] + h2[3]);
    float v2 = 0.f;
#pragma unroll
    for (int k = 0; k < 4; ++k) { float d = h2[k] - m2; v2 += d * d; }
    v2 *= 0.25f;
    float inv2 = rsqrtf(v2 + EPS);
#pragma unroll
    for (int k = 0; k < 4; ++k) {
        float t = (h2[k] - m2) * inv2 * gn2_s[k] + gn2_b[k];
        att[b * 4 + k] = 1.0f / (1.0f + expf(-t));
    }
}

// ---------------------------------------------------------------------------
// Kernel 3: aggregate weights -> bf16 in MFMA-fragment-major layout.
// chunk = ((h*9+s)*2+kb)*8 + M   (h: ic half, s: kh*3+kw, kb: ic 32-block, M: oc 16-block)
// element: lane l holds oc = M*16+(l&15), ic = h*64+kb*32+(l>>4)*8+j, j=0..7
// aggw[(b*288 + chunk)*512 + l*8 + j]  (ushort)
// One thread per (chunk,l), looping all 32 b (weight read ONCE total).
// ---------------------------------------------------------------------------
__global__ __launch_bounds__(256) void aggw_kernel(const float* __restrict__ weight,
                                                   const float* __restrict__ att,
                                                   ushort* __restrict__ aggw) {
    int t = blockIdx.x * 256 + threadIdx.x;     // 72*256 = 18432 = 288*64
    int l = t & 63;
    int chunk = t >> 6;                          // 0..287
    int M = chunk & 7;
    int c2 = chunk >> 3;
    int kb = c2 & 1;
    int c3 = c2 >> 1;                            // h*9 + s, 0..17
    int s = c3 % 9;
    int h = c3 / 9;
    int oc = M * 16 + (l & 15);
    int ic0 = h * 64 + kb * 32 + (l >> 4) * 8;

    float wv[4][8];
#pragma unroll
    for (int k = 0; k < 4; ++k)
#pragma unroll
        for (int j = 0; j < 8; ++j)
            wv[k][j] = weight[(((size_t)(k * 128 + oc)) * 128 + ic0 + j) * 9 + s];

    for (int b = 0; b < 32; ++b) {
        float a0 = att[b * 4 + 0], a1 = att[b * 4 + 1], a2 = att[b * 4 + 2], a3 = att[b * 4 + 3];
        uint pk[4];
#pragma unroll
        for (int p = 0; p < 4; ++p) {
            float f0 = a0 * wv[0][2 * p] + a1 * wv[1][2 * p] + a2 * wv[2][2 * p] + a3 * wv[3][2 * p];
            float f1 = a0 * wv[0][2 * p + 1] + a1 * wv[1][2 * p + 1] + a2 * wv[2][2 * p + 1] + a3 * wv[3][2 * p + 1];
            pk[p] = (uint)f2bf(f0) | ((uint)f2bf(f1) << 16);
        }
        uint4* dst = (uint4*)(aggw + ((size_t)(b * 288 + chunk) * 64 + l) * 8);
        *dst = make_uint4(pk[0], pk[1], pk[2], pk[3]);
    }
}

// ---------------------------------------------------------------------------
// Kernel 4: implicit-GEMM conv via MFMA.
// grid = 32(b) * 32(row-tile of 2 rows).  block = 256 = 4 waves (wm: oc-half, wn: row).
// LDS: x tile bf16 [4 halo rows][66 padded cols][64 ic], XOR-swizzled ic slots.
// Per h(ic half): stage LDS, then 9 slices * 2 kb = 18 K-steps of 16 MFMA/wave.
// ---------------------------------------------------------------------------
__global__ __launch_bounds__(256, 3) void conv_kernel(const float* __restrict__ x,
                                                      const ushort* __restrict__ aggw,
                                                      const float* __restrict__ att,
                                                      const float* __restrict__ bias,
                                                      float* __restrict__ out) {
    __shared__ ushort lds[4 * 66 * 64];          // 33792 B

    int blk = blockIdx.x;
    int b = blk >> 5;
    int y0 = (blk & 31) * 2;
    int tid = threadIdx.x;

    // zero the padded columns c=0 and c=65 (whole 64-ushort ic-rows)
    if (tid < 64) {
        int r = tid >> 4;
        int c = ((tid >> 3) & 1) * 65;
        int ch = tid & 7;
        *(uint4*)&lds[(r * 66 + c) * 64 + ch * 8] = make_uint4(0, 0, 0, 0);
    }

    int l = tid & 63, w = tid >> 6;
    int wm = w >> 1, wn = w & 1;

    f32x4 acc[4][4];
#pragma unroll
    for (int m = 0; m < 4; ++m)
#pragma unroll
        for (int n = 0; n < 4; ++n) acc[m][n] = (f32x4){0.f, 0.f, 0.f, 0.f};

    const ushort* Abase = aggw + (size_t)b * 147456 + l * 8;   // 288 chunks * 512

    // staging coords
    int cg = tid & 15;            // 4-col group
    int rr = (tid >> 4) & 3;      // halo row 0..3
    int icq = tid >> 6;           // 16-ic group
    int ystage = y0 - 1 + rr;
    bool yok = (ystage >= 0) && (ystage < 64);

    for (int h = 0; h < 2; ++h) {
        if (h) __syncthreads();   // all reads of previous half done before overwrite
        // ---- stage x half into LDS ----
#pragma unroll
        for (int ch = 0; ch < 2; ++ch) {
            float4 v[8];
#pragma unroll
            for (int i = 0; i < 8; ++i) {
                int icg = h * 64 + icq * 16 + ch * 8 + i;
                if (yok)
                    v[i] = *(const float4*)(x + (((size_t)b * 128 + icg) * 64 + ystage) * 64 + cg * 4);
                else
                    v[i] = make_float4(0.f, 0.f, 0.f, 0.f);
            }
#pragma unroll
            for (int j = 0; j < 4; ++j) {
                int c = cg * 4 + j + 1;
                const float* vf = (const float*)v;
                uint pk[4];
#pragma unroll
                for (int p = 0; p < 4; ++p) {
                    float f0 = vf[(2 * p) * 4 + j];
                    float f1 = vf[(2 * p + 1) * 4 + j];
                    pk[p] = (uint)f2bf(f0) | ((uint)f2bf(f1) << 16);
                }
                int uo = (icq * 16 + ch * 8) ^ (((c ^ rr) & 7) << 3);
                *(uint4*)&lds[(rr * 66 + c) * 64 + uo] = make_uint4(pk[0], pk[1], pk[2], pk[3]);
            }
        }
        __syncthreads();

        // ---- 18 K-steps ----
#pragma unroll
        for (int s = 0; s < 9; ++s) {
            int kh = s / 3, kw = s % 3;
            int r = wn + kh;
#pragma unroll
            for (int kb = 0; kb < 2; ++kb) {
                int chunk = ((h * 9 + s) * 2 + kb) * 8 + wm * 4;
                bf16x8 a[4];
#pragma unroll
                for (int m = 0; m < 4; ++m)
                    a[m] = *(const bf16x8*)(Abase + (size_t)(chunk + m) * 512);
                bf16x8 bf[4];
#pragma unroll
                for (int nb = 0; nb < 4; ++nb) {
                    int c = nb * 16 + (l & 15) + kw;
                    int uo = (kb * 32 + (l >> 4) * 8) ^ (((c ^ r) & 7) << 3);
                    bf[nb] = *(const bf16x8*)&lds[(r * 66 + c) * 64 + uo];
                }
#pragma unroll
                for (int m = 0; m < 4; ++m)
#pragma unroll
                    for (int nb = 0; nb < 4; ++nb)
                        acc[m][nb] = __builtin_amdgcn_mfma_f32_16x16x32_bf16(a[m], bf[nb], acc[m][nb], 0, 0, 0);
            }
        }
    }

    // ---- epilogue: + att@bias, store ----
    float a0 = att[b * 4 + 0], a1 = att[b * 4 + 1], a2 = att[b * 4 + 2], a3 = att[b * 4 + 3];
    int row = y0 + wn;
#pragma unroll
    for (int m = 0; m < 4; ++m) {
#pragma unroll
        for (int q = 0; q < 4; ++q) {
            int oc = wm * 64 + m * 16 + (l >> 4) * 4 + q;
            float ab = a0 * bias[oc] + a1 * bias[128 + oc] + a2 * bias[256 + oc] + a3 * bias[384 + oc];
            float* ob = out + (((size_t)b * 128 + oc) * 64 + row) * 64;
#pragma unroll
            for (int nb = 0; nb < 4; ++nb)
                ob[nb * 16 + (l & 15)] = acc[m][nb][q] + ab;
        }
    }
}

// ---------------------------------------------------------------------------
extern "C" void kernel_launch(void* const* d_in, const int* in_sizes, int n_in,
                              void* d_out, int out_size, void* d_ws, size_t ws_size,
                              hipStream_t stream) {
    const float* x      = (const float*)d_in[0];
    const float* weight = (const float*)d_in[1];
    const float* bias   = (const float*)d_in[2];
    const float* se_w1  = (const float*)d_in[3];
    const float* gn1_s  = (const float*)d_in[4];
    const float* gn1_b  = (const float*)d_in[5];
    const float* se_w2  = (const float*)d_in[6];
    const float* gn2_s  = (const float*)d_in[7];
    const float* gn2_b  = (const float*)d_in[8];
    float* out = (float*)d_out;

    float*  pooled = (float*)d_ws;                       // 4096 floats
    float*  att    = (float*)((char*)d_ws + 16384);      // 128 floats
    ushort* aggw   = (ushort*)((char*)d_ws + 32768);     // 32*288*512 ushorts = 9.44 MB

    pool_kernel<<<32 * 128, 256, 0, stream>>>(x, pooled);
    se_kernel<<<1, 64, 0, stream>>>(pooled, se_w1, gn1_s, gn1_b, se_w2, gn2_s, gn2_b, att);
    aggw_kernel<<<72, 256, 0, stream>>>(weight, att, aggw);
    conv_kernel<<<32 * 32, 256, 0, stream>>>(x, aggw, att, bias, out);
}